// Round 8
// baseline (199.311 us; speedup 1.0000x reference)
//
#include <hip/hip_runtime.h>

// ---------------- problem constants ----------------
constexpr int BS = 4, P_PER = 12000, NP = BS * P_PER;      // 48000 pillars
constexpr int XL = 432, YL = 496, NPTS = 32;
constexpr int XQ = XL / 4;                                 // 108 float4 per row
constexpr int NS = 3 * NPTS;                               // 96 (c,k) slabs
constexpr int YX = YL * XL;                                // 214272

constexpr long long SZ_P   = (long long)NP * NPTS * 3;        // 4,608,000
constexpr long long SZ_C   = (long long)NP * 3;               // 144,000
constexpr long long SZ_N   = NP;                              // 48,000
constexpr long long SZ_ALL = (long long)BS * 3 * NPTS * YL * XL; // 82,280,448
constexpr long long SZ_CTR = (long long)BS * 3 * YL * XL;     // 2,571,264

constexpr long long OFF_ALL = SZ_P + SZ_C + SZ_N;             // 4,800,000
constexpr long long OFF_CTR = OFF_ALL + SZ_ALL;               // 87,080,448

constexpr int MAXJ = 48;    // staged pillars per chunk (row mean 24.2, 5 sigma)
constexpr int JCAP = 127;   // col2j is int8; j >= JCAP treated as empty
constexpr int OUCAP = 112;  // occupied-unit list capacity (<= XQ)

// clang ext-vector float4 — accepted by __builtin_nontemporal_store
typedef float nt4 __attribute__((ext_vector_type(4)));

// mega-kernel block partition
constexpr int NB_ROW  = BS * YL;                                  // 1984
constexpr int NB_CVT  = (int)((SZ_C / 4 + SZ_N / 4 + 255) / 256); // 188
constexpr int NB_COPY = (int)(SZ_P / 4 / 256);                    // 4500 exact
constexpr int NB_MEGA = NB_ROW + NB_CVT + NB_COPY;                // 6672

// ---------------- map build: cell -> pillar index ----------------
__global__ __launch_bounds__(256) void build_map(const int* __restrict__ coors,
                                                 int* __restrict__ map)
{
    int p = blockIdx.x * 256 + threadIdx.x;
    if (p >= NP) return;
    int b  = coors[3 * p + 0];
    int ix = coors[3 * p + 1];
    int iy = coors[3 * p + 2];
    map[(b * YL + iy) * XL + ix] = p;
}

// ---------------- mega kernel: rows + convert + copy in one grid ----------------
__global__ __launch_bounds__(256) void mega_kernel(
    const float* __restrict__ pillars, const int* __restrict__ coors,
    const int* __restrict__ npoints, const int* __restrict__ map,
    float* __restrict__ out)
{
    const int bid = blockIdx.x;
    const int t   = threadIdx.x;

    if (bid >= NB_ROW) {
        if (bid < NB_ROW + NB_CVT) {
            // outputs 1,2: coors / npoints int32 -> float32
            constexpr int NC = (int)(SZ_C / 4);   // 36000 int4 units
            constexpr int NN = (int)(SZ_N / 4);   // 12000
            int u = (bid - NB_ROW) * 256 + t;
            if (u >= NC + NN) return;
            int4 a; long long dst;
            if (u < NC) { a = reinterpret_cast<const int4*>(coors)[u]; dst = SZ_P / 4 + u; }
            else { a = reinterpret_cast<const int4*>(npoints)[u - NC]; dst = SZ_P / 4 + NC + (u - NC); }
            nt4 o = {(float)a.x, (float)a.y, (float)a.z, (float)a.w};
            __builtin_nontemporal_store(o, reinterpret_cast<nt4*>(out) + dst);
        } else {
            // output region 0: pillars passthrough, fully coalesced
            long long u = (long long)(bid - NB_ROW - NB_CVT) * 256 + t; // < 1,152,000
            nt4 v = reinterpret_cast<const nt4*>(pillars)[u];
            __builtin_nontemporal_store(v, reinterpret_cast<nt4*>(out) + u);
        }
        return;
    }

    // ---- row section: one block per (b, iy), 4 waves ----
    __shared__ float data[MAXJ][97];        // 18,624 B
    __shared__ float ctr[MAXJ * 3];         //    576 B
    __shared__ signed char col2j[XL];       //    432 B
    __shared__ int jlist[JCAP + 1];         //    512 B
    __shared__ unsigned short occx[JCAP + 1];  // 256 B  (j -> column)
    __shared__ unsigned short occu[OUCAP];     // 224 B  (occupied float4 units)
    __shared__ unsigned int ubit[4];           // unit-occupancy bitmap (108 bits)
    __shared__ int cnt, nou;

    const int b    = bid / YL;
    const int iy   = bid % YL;
    const int wave = t >> 6;
    const int lane = t & 63;

    if (t == 0) { cnt = 0; nou = 0; }
    if (t < 4) ubit[t] = 0;
    __syncthreads();

    const int* mrow = map + (b * YL + iy) * XL;
    for (int x = t; x < XL; x += 256) {
        int p = mrow[x];
        if (p >= 0) {
            int j = atomicAdd(&cnt, 1);
            if (j < JCAP) {
                jlist[j] = p; occx[j] = (unsigned short)x;
                col2j[x] = (signed char)j;
            } else col2j[x] = -1;
        } else {
            col2j[x] = -1;
        }
    }
    __syncthreads();
    const int nOcc = (cnt < JCAP) ? cnt : JCAP;
    const int nChunks = (nOcc <= MAXJ) ? 1 : (nOcc + MAXJ - 1) / MAXJ;

    // occupied-unit list + bitmap (threads 0..XQ-1); runs alongside staging
    if (t < XQ) {
        unsigned int cc = reinterpret_cast<const unsigned int*>(col2j)[t];
        if (cc != 0xFFFFFFFFu) {
            int idx = atomicAdd(&nou, 1);
            if (idx < OUCAP) occu[idx] = (unsigned short)t;
            atomicOr(&ubit[t >> 5], 1u << (t & 31));
        }
    }

    float* out_all = out + OFF_ALL + (long long)b * NS * YX + (long long)iy * XL;
    float* out_ctr = out + OFF_CTR + (long long)b * 3 * YX + (long long)iy * XL;
    const float* dflat = &data[0][0];
    const nt4 z4 = {0.f, 0.f, 0.f, 0.f};

    for (int ch = 0; ch < nChunks; ++ch) {
        const int jbase = ch * MAXJ;
        int chunkN = nOcc - jbase;
        if (chunkN > MAXJ) chunkN = MAXJ;
        if (chunkN < 0) chunkN = 0;

        // stage pillar data: 24 float4 per pillar, read once chip-wide
        for (int i = t; i < chunkN * 24; i += 256) {
            int jl = i / 24, e4 = i % 24;
            float4 v = reinterpret_cast<const float4*>(pillars)
                           [(long long)jlist[jbase + jl] * 24 + e4];
            data[jl][e4 * 4 + 0] = v.x;
            data[jl][e4 * 4 + 1] = v.y;
            data[jl][e4 * 4 + 2] = v.z;
            data[jl][e4 * 4 + 3] = v.w;
        }
        __syncthreads();

        // centers from staged data
        for (int i = t; i < chunkN * 3; i += 256) {
            int jl = i / 3, c = i % 3;
            float s = 0.f;
#pragma unroll
            for (int k = 0; k < NPTS; ++k) s += data[jl][k * 3 + c];
            ctr[i] = s / (float)npoints[jlist[jbase + jl]];
        }
        __syncthreads();

        if (ch == 0) {
            // ---- hoisted, slab-invariant per-lane state ----
            // pass-1 predicates: lane's two units, true if unit has NO occupied cell
            const int ua = lane, ub = lane + 64;
            const bool za = !((ubit[ua >> 5] >> (ua & 31)) & 1u);
            const bool zb = (ub < XQ) && !((ubit[ub >> 5] >> (ub & 31)) & 1u);
            // pass-2: lane <-> occupied unit binding
            const int nouC = (nou < OUCAP) ? nou : OUCAP;
            const bool act = lane < nouC;
            const int  uo  = act ? (int)occu[lane] : 0;
            const unsigned int cc = act
                ? reinterpret_cast<const unsigned int*>(col2j)[uo] : 0xFFFFFFFFu;
            const int j0 = (int)(signed char)(cc & 0xff);
            const int j1 = (int)(signed char)((cc >> 8) & 0xff);
            const int j2 = (int)(signed char)((cc >> 16) & 0xff);
            const int j3 = (int)(signed char)(cc >> 24);
            const bool v0 = (unsigned)j0 < (unsigned)MAXJ;
            const bool v1 = (unsigned)j1 < (unsigned)MAXJ;
            const bool v2 = (unsigned)j2 < (unsigned)MAXJ;
            const bool v3 = (unsigned)j3 < (unsigned)MAXJ;
            const int a0 = (v0 ? j0 : 0) * 97;
            const int a1 = (v1 ? j1 : 0) * 97;
            const int a2 = (v2 ? j2 : 0) * 97;
            const int a3 = (v3 ? j3 : 0) * 97;

            // ---- pillar_all: wave w owns slabs [24w, 24w+24) ----
            {
                float* rowp = out_all + (long long)(wave * 24) * YX;
                for (int s = wave * 24, send = s + 24; s < send; ++s, rowp += YX) {
                    const int e = (s & 31) * 3 + (s >> 5);
                    if (za) __builtin_nontemporal_store(z4, reinterpret_cast<nt4*>(rowp) + ua);
                    if (zb) __builtin_nontemporal_store(z4, reinterpret_cast<nt4*>(rowp) + ub);
                    if (act) {
                        nt4 o;
                        o.x = v0 ? dflat[a0 + e] : 0.f;
                        o.y = v1 ? dflat[a1 + e] : 0.f;
                        o.z = v2 ? dflat[a2 + e] : 0.f;
                        o.w = v3 ? dflat[a3 + e] : 0.f;
                        __builtin_nontemporal_store(o, reinterpret_cast<nt4*>(rowp) + uo);
                    }
                }
                // rare: more than 64 occupied units (needs nOcc > 64; ~never)
                if (nouC > 64) {
                    for (int s = wave * 24, send = s + 24; s < send; ++s) {
                        const int e = (s & 31) * 3 + (s >> 5);
                        float* rp = out_all + (long long)s * YX;
                        for (int l = 64 + lane; l < nouC; l += 64) {
                            int uu = occu[l];
                            unsigned int c2 = reinterpret_cast<const unsigned int*>(col2j)[uu];
                            nt4 o;
                            int k0 = (int)(signed char)(c2 & 0xff);
                            int k1 = (int)(signed char)((c2 >> 8) & 0xff);
                            int k2 = (int)(signed char)((c2 >> 16) & 0xff);
                            int k3 = (int)(signed char)(c2 >> 24);
                            o.x = ((unsigned)k0 < MAXJ) ? data[k0][e] : 0.f;
                            o.y = ((unsigned)k1 < MAXJ) ? data[k1][e] : 0.f;
                            o.z = ((unsigned)k2 < MAXJ) ? data[k2][e] : 0.f;
                            o.w = ((unsigned)k3 < MAXJ) ? data[k3][e] : 0.f;
                            __builtin_nontemporal_store(o, reinterpret_cast<nt4*>(rp) + uu);
                        }
                    }
                }
            }
            // ---- pillar_center: waves 0..2 own c = wave ----
            if (wave < 3) {
                float* rowp = out_ctr + (long long)wave * YX;
                if (za) __builtin_nontemporal_store(z4, reinterpret_cast<nt4*>(rowp) + ua);
                if (zb) __builtin_nontemporal_store(z4, reinterpret_cast<nt4*>(rowp) + ub);
                if (act) {
                    nt4 o;
                    o.x = v0 ? ctr[j0 * 3 + wave] : 0.f;
                    o.y = v1 ? ctr[j1 * 3 + wave] : 0.f;
                    o.z = v2 ? ctr[j2 * 3 + wave] : 0.f;
                    o.w = v3 ? ctr[j3 * 3 + wave] : 0.f;
                    __builtin_nontemporal_store(o, reinterpret_cast<nt4*>(rowp) + uo);
                }
                if (nouC > 64) {
                    for (int l = 64 + lane; l < nouC; l += 64) {
                        int uu = occu[l];
                        unsigned int c2 = reinterpret_cast<const unsigned int*>(col2j)[uu];
                        nt4 o;
                        int k0 = (int)(signed char)(c2 & 0xff);
                        int k1 = (int)(signed char)((c2 >> 8) & 0xff);
                        int k2 = (int)(signed char)((c2 >> 16) & 0xff);
                        int k3 = (int)(signed char)(c2 >> 24);
                        o.x = ((unsigned)k0 < MAXJ) ? ctr[k0 * 3 + wave] : 0.f;
                        o.y = ((unsigned)k1 < MAXJ) ? ctr[k1 * 3 + wave] : 0.f;
                        o.z = ((unsigned)k2 < MAXJ) ? ctr[k2 * 3 + wave] : 0.f;
                        o.w = ((unsigned)k3 < MAXJ) ? ctr[k3 * 3 + wave] : 0.f;
                        __builtin_nontemporal_store(o, reinterpret_cast<nt4*>(rowp) + uu);
                    }
                }
            }
        } else {
            // overflow chunk (statistically never): sparse per-cell overwrites,
            // ordered vs ch0 by the preceding __syncthreads (vmcnt drain)
            for (int s = wave * 24, send = s + 24; s < send; ++s) {
                const int e = (s & 31) * 3 + (s >> 5);
                if (lane < chunkN)
                    out_all[(long long)s * YX + occx[jbase + lane]] = data[lane][e];
            }
            if (wave < 3 && lane < chunkN)
                out_ctr[(long long)wave * YX + occx[jbase + lane]] = ctr[lane * 3 + wave];
        }
        __syncthreads();
    }
}

// ---------------- fallback path (ws too small): memset + scatter ----------------
__global__ __launch_bounds__(256) void scatter_kernel(
    const float* __restrict__ pillars, const int* __restrict__ coors,
    const int* __restrict__ npoints, float* __restrict__ out)
{
    int tid = blockIdx.x * blockDim.x + threadIdx.x;
    if (tid < NP * NPTS) {
        int p = tid / NPTS, k = tid % NPTS;
        int b = coors[3 * p], ix = coors[3 * p + 1], iy = coors[3 * p + 2];
#pragma unroll
        for (int c = 0; c < 3; ++c) {
            float val = pillars[(long long)p * 96 + k * 3 + c];
            long long e = OFF_ALL + ((((long long)(b * 3 + c) * NPTS + k) * YL + iy) * XL + ix);
            out[e] = val;
        }
    } else if (tid < NP * NPTS + NP) {
        int p = tid - NP * NPTS;
        int b = coors[3 * p], ix = coors[3 * p + 1], iy = coors[3 * p + 2];
        const float4* src = reinterpret_cast<const float4*>(pillars + (long long)p * 96);
        float s[3] = {0.f, 0.f, 0.f};
#pragma unroll
        for (int i = 0; i < 24; ++i) {
            float4 q = src[i];
            s[(4 * i + 0) % 3] += q.x;
            s[(4 * i + 1) % 3] += q.y;
            s[(4 * i + 2) % 3] += q.z;
            s[(4 * i + 3) % 3] += q.w;
        }
        float inv = 1.0f / (float)npoints[p];
#pragma unroll
        for (int c = 0; c < 3; ++c) {
            long long e = OFF_CTR + (((long long)(b * 3 + c) * YL + iy) * XL + ix);
            out[e] = s[c] * inv;
        }
    }
}

__global__ __launch_bounds__(256) void smallcvt_kernel(
    const int* __restrict__ coors, const int* __restrict__ npoints,
    float* __restrict__ out)
{
    constexpr int NC = (int)(SZ_C / 4);
    constexpr int NN = (int)(SZ_N / 4);
    int u = blockIdx.x * 256 + threadIdx.x;
    if (u >= NC + NN) return;
    int4 a; long long dst;
    if (u < NC) { a = reinterpret_cast<const int4*>(coors)[u]; dst = SZ_P / 4 + u; }
    else { a = reinterpret_cast<const int4*>(npoints)[u - NC]; dst = SZ_P / 4 + NC + (u - NC); }
    reinterpret_cast<float4*>(out)[dst] =
        float4{(float)a.x, (float)a.y, (float)a.z, (float)a.w};
}

extern "C" void kernel_launch(void* const* d_in, const int* in_sizes, int n_in,
                              void* d_out, int out_size, void* d_ws, size_t ws_size,
                              hipStream_t stream) {
    const float* pillars = (const float*)d_in[0];
    const int*   coors   = (const int*)d_in[1];
    const int*   npoints = (const int*)d_in[2];
    float*       out     = (float*)d_out;

    const size_t mapBytes = (size_t)BS * YL * XL * sizeof(int);   // 3,428,352

    if (ws_size >= mapBytes) {
        int* map = (int*)d_ws;
        (void)hipMemsetAsync(map, 0xFF, mapBytes, stream);        // all cells -> -1
        build_map<<<(NP + 255) / 256, 256, 0, stream>>>(coors, map);
        mega_kernel<<<NB_MEGA, 256, 0, stream>>>(pillars, coors, npoints, map, out);
    } else {
        // fallback: zero big regions, copy/convert small regions, scatter
        (void)hipMemcpyAsync(out, pillars, (size_t)SZ_P * sizeof(float),
                             hipMemcpyDeviceToDevice, stream);
        (void)hipMemsetAsync(out + OFF_ALL, 0, (size_t)(SZ_ALL + SZ_CTR) * sizeof(float), stream);
        smallcvt_kernel<<<(int)((SZ_C / 4 + SZ_N / 4 + 255) / 256), 256, 0, stream>>>(
            coors, npoints, out);
        int nthr = NP * NPTS + NP;
        scatter_kernel<<<(nthr + 255) / 256, 256, 0, stream>>>(pillars, coors, npoints, out);
    }
}

// Round 9
// 103.911 us; speedup vs baseline: 1.9181x; 1.9181x over previous
//
#include <hip/hip_runtime.h>

// ---------------- problem constants ----------------
constexpr int BS = 4, P_PER = 12000, NP = BS * P_PER;      // 48000 pillars
constexpr int XL = 432, YL = 496, NPTS = 32;
constexpr int XQ = XL / 4;                                 // 108 float4 per row
constexpr int NS = 3 * NPTS;                               // 96 (c,k) slabs
constexpr int YX = YL * XL;                                // 214272
constexpr int NROW = BS * YL;                              // 1984

constexpr long long SZ_P   = (long long)NP * NPTS * 3;        // 4,608,000
constexpr long long SZ_C   = (long long)NP * 3;               // 144,000
constexpr long long SZ_N   = NP;                              // 48,000
constexpr long long SZ_ALL = (long long)BS * 3 * NPTS * YL * XL; // 82,280,448
constexpr long long SZ_CTR = (long long)BS * 3 * YL * XL;     // 2,571,264

constexpr long long OFF_ALL = SZ_P + SZ_C + SZ_N;             // 4,800,000
constexpr long long OFF_CTR = OFF_ALL + SZ_ALL;               // 87,080,448

// clang ext-vector float4 — accepted by __builtin_nontemporal_store
typedef float nt4 __attribute__((ext_vector_type(4)));

// ---------------- workspace layout (fast path) ----------------
constexpr size_t WS_MAP   = 0;                                // int[NROW*XL]
constexpr size_t WS_RCNT  = WS_MAP  + (size_t)NROW * XL * 4;  // int[NROW]
constexpr size_t WS_RMAP2 = WS_RCNT + (size_t)NROW * 4;       // uint2[NROW*XQ]
constexpr size_t WS_PW    = WS_RMAP2 + (size_t)NROW * XQ * 8; // float[99*48000]
constexpr size_t WS_NEED  = WS_PW + (size_t)99 * NP * 4;      // 24,158,464

constexpr int PWLD = NP;        // pw leading dim (48000)
constexpr int MAXJ = 64;        // staged pillars per chunk (mean 24.2/row)
constexpr int PCAP = 128;       // ordered pillar-list capacity per row

// bigfill block partition: 16-iy windows
constexpr int NWIN    = YL / 16;                               // 31
constexpr int NB_ALL  = BS * NS * NWIN;                        // 11904
constexpr int NB_CTR  = BS * 3 * NWIN;                         // 372
constexpr int NB_CVT  = (int)((SZ_C / 4 + SZ_N / 4 + 255) / 256); // 188
constexpr int NB_COPY = (int)(SZ_P / 4 / 256);                 // 4500 exact
constexpr int NB_BIG  = NB_ALL + NB_CTR + NB_CVT + NB_COPY;    // 16964

// ---------------- map build: cell -> pillar index, + per-row counts ----------
__global__ __launch_bounds__(256) void build_map2(const int* __restrict__ coors,
                                                  int* __restrict__ map,
                                                  int* __restrict__ rowcnt)
{
    int p = blockIdx.x * 256 + threadIdx.x;
    if (p >= NP) return;
    int b  = coors[3 * p + 0];
    int ix = coors[3 * p + 1];
    int iy = coors[3 * p + 2];
    int row = b * YL + iy;
    map[row * XL + ix] = p;
    atomicAdd(&rowcnt[row], 1);
}

// prefix popcount of bits [0, x) in a row bitmap
static __device__ __forceinline__ int pfx(const unsigned int* bm, int x) {
    int w = x >> 5, r = 0;
    for (int i = 0; i < w; ++i) r += __popc(bm[i]);
    r += __popc(bm[w] & ((1u << (x & 31)) - 1u));
    return r;
}

// ---------------- rowfill: ranks, rmap2 table, rank-ordered transpose pw -------
__global__ __launch_bounds__(256) void rowfill(
    const float* __restrict__ pillars, const int* __restrict__ npoints,
    const int* __restrict__ map, const int* __restrict__ rowcnt,
    uint2* __restrict__ rmap2, float* __restrict__ pw)
{
    __shared__ float data[MAXJ][97];        // 24,832 B
    __shared__ float ctrv[MAXJ * 3];        //    768 B
    __shared__ unsigned int bmap[14];       // 432-bit row occupancy
    __shared__ int plist[PCAP];             // rank -> pillar index (ordered!)
    __shared__ int rbase_sh;

    const int row = blockIdx.x;             // 0..NROW-1
    const int t   = threadIdx.x;
    const int lane = t & 63;

    if (t < 14) bmap[t] = 0;
    if (t == 0) rbase_sh = 0;
    __syncthreads();

    const int* mrow = map + row * XL;
    // occupancy bitmap + rowbase partial sum (independent work, same pass)
    for (int x = t; x < XL; x += 256)
        if (mrow[x] >= 0) atomicOr(&bmap[x >> 5], 1u << (x & 31));
    int partial = 0;
    for (int r = t; r < row; r += 256) partial += rowcnt[r];
    for (int o = 32; o > 0; o >>= 1) partial += __shfl_down(partial, o);
    if (lane == 0) atomicAdd(&rbase_sh, partial);
    __syncthreads();
    const int rbase = rbase_sh;

    // ordered pillar list: rank = prefix popcount (deterministic)
    for (int x = t; x < XL; x += 256) {
        int p = mrow[x];
        if (p >= 0) {
            int rl = pfx(bmap, x);
            if (rl < PCAP) plist[rl] = p;
        }
    }
    __syncthreads();

    // per-unit rank table: {base, 4-bit mask}
    if (t < XQ) {
        int x0 = 4 * t;
        unsigned int m4 = (bmap[x0 >> 5] >> (x0 & 31)) & 0xFu;
        rmap2[row * XQ + t] = uint2{(unsigned int)(rbase + pfx(bmap, x0)), m4};
    }

    int n = rowcnt[row];
    if (n > PCAP) n = PCAP;
    const int nChunks = (n + MAXJ - 1) / MAXJ;

    for (int ch = 0; ch < nChunks; ++ch) {
        const int jb = ch * MAXJ;
        int cN = n - jb;
        if (cN > MAXJ) cN = MAXJ;

        // stage pillar data: 24 float4 per pillar, read once chip-wide
        for (int i = t; i < cN * 24; i += 256) {
            int jl = i / 24, e4 = i % 24;
            float4 v = reinterpret_cast<const float4*>(pillars)
                           [(long long)plist[jb + jl] * 24 + e4];
            data[jl][e4 * 4 + 0] = v.x;
            data[jl][e4 * 4 + 1] = v.y;
            data[jl][e4 * 4 + 2] = v.z;
            data[jl][e4 * 4 + 3] = v.w;
        }
        __syncthreads();
        // centers
        for (int i = t; i < cN * 3; i += 256) {
            int jl = i / 3, c = i % 3;
            float s = 0.f;
#pragma unroll
            for (int k = 0; k < NPTS; ++k) s += data[jl][k * 3 + c];
            ctrv[i] = s / (float)npoints[plist[jb + jl]];
        }
        __syncthreads();
        // transpose to pw: 99 element-rows (96 data + 3 center), rank-contiguous
        for (int idx = t; idx < 99 * cN; idx += 256) {
            int e = idx / cN, i = idx - e * cN;
            float val = (e < 96) ? data[i][e] : ctrv[i * 3 + (e - 96)];
            pw[(long long)e * PWLD + rbase + jb + i] = val;
        }
        __syncthreads();
    }
}

// ---------------- bigfill: pure linear writes of all of d_out ----------------
__global__ __launch_bounds__(256) void bigfill(
    const float* __restrict__ pillars, const int* __restrict__ coors,
    const int* __restrict__ npoints, const uint2* __restrict__ rmap2,
    const float* __restrict__ pw, float* __restrict__ out)
{
    const int bid = blockIdx.x;
    const int t   = threadIdx.x;

    if (bid < NB_ALL + NB_CTR) {
        int e, iy0, b;
        float* dst;
        if (bid < NB_ALL) {
            int w = bid % NWIN;
            int s = (bid / NWIN) % NS;
            b     = bid / (NWIN * NS);
            e     = (s & 31) * 3 + (s >> 5);
            iy0   = w * 16;
            dst   = out + OFF_ALL + ((long long)(b * NS + s)) * YX + (long long)iy0 * XL;
        } else {
            int t2 = bid - NB_ALL;
            int w = t2 % NWIN;
            int c = (t2 / NWIN) % 3;
            b     = t2 / (NWIN * 3);
            e     = 96 + c;
            iy0   = w * 16;
            dst   = out + OFF_CTR + ((long long)(b * 3 + c)) * YX + (long long)iy0 * XL;
        }
        const uint2* rm = rmap2 + (b * YL + iy0) * XQ;     // 1728 units, coalesced
        const float* pwe = pw + (long long)e * PWLD;       // ~1.5 KB window, L1
        nt4* dst4 = reinterpret_cast<nt4*>(dst);
        for (int u = t; u < 16 * XQ; u += 256) {
            uint2 rv = rm[u];
            nt4 o = {0.f, 0.f, 0.f, 0.f};
            unsigned int m = rv.y;
            if (m) {
                unsigned int base = rv.x;
                if (m & 1u) o.x = pwe[base];
                if (m & 2u) o.y = pwe[base + __popc(m & 1u)];
                if (m & 4u) o.z = pwe[base + __popc(m & 3u)];
                if (m & 8u) o.w = pwe[base + __popc(m & 7u)];
            }
            __builtin_nontemporal_store(o, dst4 + u);
        }
        return;
    }
    if (bid < NB_ALL + NB_CTR + NB_CVT) {
        // outputs 1,2: coors / npoints int32 -> float32
        constexpr int NC = (int)(SZ_C / 4);   // 36000 int4 units
        constexpr int NN = (int)(SZ_N / 4);   // 12000
        int u = (bid - NB_ALL - NB_CTR) * 256 + t;
        if (u >= NC + NN) return;
        int4 a; long long dst;
        if (u < NC) { a = reinterpret_cast<const int4*>(coors)[u]; dst = SZ_P / 4 + u; }
        else { a = reinterpret_cast<const int4*>(npoints)[u - NC]; dst = SZ_P / 4 + NC + (u - NC); }
        nt4 o = {(float)a.x, (float)a.y, (float)a.z, (float)a.w};
        __builtin_nontemporal_store(o, reinterpret_cast<nt4*>(out) + dst);
        return;
    }
    // output region 0: pillars passthrough, fully coalesced
    long long u = (long long)(bid - NB_ALL - NB_CTR - NB_CVT) * 256 + t;
    nt4 v = reinterpret_cast<const nt4*>(pillars)[u];
    __builtin_nontemporal_store(v, reinterpret_cast<nt4*>(out) + u);
}

// ================= fallback: proven round-6 path (needs only 3.4 MB ws) =======
constexpr int F_MAXJ = 48;
constexpr int F_JCAP = 127;
constexpr int F_NB_ROW  = NROW;
constexpr int F_NB_CVT  = NB_CVT;
constexpr int F_NB_COPY = NB_COPY;
constexpr int F_NB_MEGA = F_NB_ROW + F_NB_CVT + F_NB_COPY;

__global__ __launch_bounds__(256) void build_map(const int* __restrict__ coors,
                                                 int* __restrict__ map)
{
    int p = blockIdx.x * 256 + threadIdx.x;
    if (p >= NP) return;
    map[(coors[3 * p] * YL + coors[3 * p + 2]) * XL + coors[3 * p + 1]] = p;
}

__global__ __launch_bounds__(256) void mega_kernel(
    const float* __restrict__ pillars, const int* __restrict__ coors,
    const int* __restrict__ npoints, const int* __restrict__ map,
    float* __restrict__ out)
{
    const int bid = blockIdx.x;
    const int t   = threadIdx.x;

    if (bid >= F_NB_ROW) {
        if (bid < F_NB_ROW + F_NB_CVT) {
            constexpr int NC = (int)(SZ_C / 4);
            constexpr int NN = (int)(SZ_N / 4);
            int u = (bid - F_NB_ROW) * 256 + t;
            if (u >= NC + NN) return;
            int4 a; long long dst;
            if (u < NC) { a = reinterpret_cast<const int4*>(coors)[u]; dst = SZ_P / 4 + u; }
            else { a = reinterpret_cast<const int4*>(npoints)[u - NC]; dst = SZ_P / 4 + NC + (u - NC); }
            nt4 o = {(float)a.x, (float)a.y, (float)a.z, (float)a.w};
            __builtin_nontemporal_store(o, reinterpret_cast<nt4*>(out) + dst);
        } else {
            long long u = (long long)(bid - F_NB_ROW - F_NB_CVT) * 256 + t;
            nt4 v = reinterpret_cast<const nt4*>(pillars)[u];
            __builtin_nontemporal_store(v, reinterpret_cast<nt4*>(out) + u);
        }
        return;
    }

    __shared__ float data[F_MAXJ][97];
    __shared__ float ctr[F_MAXJ * 3];
    __shared__ signed char col2j[XL];
    __shared__ int jlist[F_JCAP + 1];
    __shared__ int cnt;

    const int b  = bid / YL;
    const int iy = bid % YL;

    if (t == 0) cnt = 0;
    __syncthreads();

    const int* mrow = map + (b * YL + iy) * XL;
    for (int x = t; x < XL; x += 256) {
        int p = mrow[x];
        if (p >= 0) {
            int j = atomicAdd(&cnt, 1);
            if (j < F_JCAP) { jlist[j] = p; col2j[x] = (signed char)j; }
            else col2j[x] = -1;
        } else col2j[x] = -1;
    }
    __syncthreads();
    const int nOcc = (cnt < F_JCAP) ? cnt : F_JCAP;
    const int nChunks = (nOcc <= F_MAXJ) ? 1 : (nOcc + F_MAXJ - 1) / F_MAXJ;

    float* out_all = out + OFF_ALL + (long long)b * NS * YX + (long long)iy * XL;
    float* out_ctr = out + OFF_CTR + (long long)b * 3 * YX + (long long)iy * XL;

    for (int ch = 0; ch < nChunks; ++ch) {
        const int jbase = ch * F_MAXJ;
        int chunkN = nOcc - jbase;
        if (chunkN > F_MAXJ) chunkN = F_MAXJ;
        if (chunkN < 0) chunkN = 0;

        for (int i = t; i < chunkN * 24; i += 256) {
            int jl = i / 24, e4 = i % 24;
            float4 v = reinterpret_cast<const float4*>(pillars)
                           [(long long)jlist[jbase + jl] * 24 + e4];
            data[jl][e4 * 4 + 0] = v.x;
            data[jl][e4 * 4 + 1] = v.y;
            data[jl][e4 * 4 + 2] = v.z;
            data[jl][e4 * 4 + 3] = v.w;
        }
        __syncthreads();
        for (int i = t; i < chunkN * 3; i += 256) {
            int jl = i / 3, c = i % 3;
            float s = 0.f;
#pragma unroll
            for (int k = 0; k < NPTS; ++k) s += data[jl][k * 3 + c];
            ctr[i] = s / (float)npoints[jlist[jbase + jl]];
        }
        __syncthreads();

        if (ch == 0) {
            {
                int s = t / XQ;
                int q = t - s * XQ;
                float* pa = out_all + (long long)s * YX + (long long)q * 4;
                const unsigned int* cj4 = reinterpret_cast<const unsigned int*>(col2j);
                for (int i = t; i < NS * XQ; i += 256) {
                    int e = (s & 31) * 3 + (s >> 5);
                    unsigned int cc = cj4[q];
                    nt4 o;
                    int j0 = (int)(signed char)(cc & 0xff);
                    int j1 = (int)(signed char)((cc >> 8) & 0xff);
                    int j2 = (int)(signed char)((cc >> 16) & 0xff);
                    int j3 = (int)(signed char)(cc >> 24);
                    o.x = ((unsigned)j0 < F_MAXJ) ? data[j0][e] : 0.f;
                    o.y = ((unsigned)j1 < F_MAXJ) ? data[j1][e] : 0.f;
                    o.z = ((unsigned)j2 < F_MAXJ) ? data[j2][e] : 0.f;
                    o.w = ((unsigned)j3 < F_MAXJ) ? data[j3][e] : 0.f;
                    __builtin_nontemporal_store(o, reinterpret_cast<nt4*>(pa));
                    s += 2; q += 40;
                    long long step = 2LL * YX + 160;
                    if (q >= XQ) { q -= XQ; s += 1; step = 3LL * YX - 272; }
                    pa += step;
                }
            }
            {
                const unsigned int* cj4 = reinterpret_cast<const unsigned int*>(col2j);
                for (int i = t; i < 3 * XQ; i += 256) {
                    int c = i / XQ, q = i - c * XQ;
                    unsigned int cc = cj4[q];
                    nt4 o;
                    int j0 = (int)(signed char)(cc & 0xff);
                    int j1 = (int)(signed char)((cc >> 8) & 0xff);
                    int j2 = (int)(signed char)((cc >> 16) & 0xff);
                    int j3 = (int)(signed char)(cc >> 24);
                    o.x = ((unsigned)j0 < F_MAXJ) ? ctr[j0 * 3 + c] : 0.f;
                    o.y = ((unsigned)j1 < F_MAXJ) ? ctr[j1 * 3 + c] : 0.f;
                    o.z = ((unsigned)j2 < F_MAXJ) ? ctr[j2 * 3 + c] : 0.f;
                    o.w = ((unsigned)j3 < F_MAXJ) ? ctr[j3 * 3 + c] : 0.f;
                    __builtin_nontemporal_store(o,
                        reinterpret_cast<nt4*>(out_ctr + (long long)c * YX + q * 4));
                }
            }
        } else {
            for (int i = t; i < XL * NS; i += 256) {
                int x = i % XL, s = i / XL;
                int j = col2j[x];
                if (j >= jbase && j < jbase + chunkN) {
                    int e = (s & 31) * 3 + (s >> 5);
                    out_all[(long long)s * YX + x] = data[j - jbase][e];
                }
            }
            for (int i = t; i < XL * 3; i += 256) {
                int x = i % XL, c = i / XL;
                int j = col2j[x];
                if (j >= jbase && j < jbase + chunkN)
                    out_ctr[(long long)c * YX + x] = ctr[(j - jbase) * 3 + c];
            }
        }
        __syncthreads();
    }
}

extern "C" void kernel_launch(void* const* d_in, const int* in_sizes, int n_in,
                              void* d_out, int out_size, void* d_ws, size_t ws_size,
                              hipStream_t stream) {
    const float* pillars = (const float*)d_in[0];
    const int*   coors   = (const int*)d_in[1];
    const int*   npoints = (const int*)d_in[2];
    float*       out     = (float*)d_out;
    char*        ws      = (char*)d_ws;

    if (ws_size >= WS_NEED) {
        int*   map    = (int*)(ws + WS_MAP);
        int*   rowcnt = (int*)(ws + WS_RCNT);
        uint2* rmap2  = (uint2*)(ws + WS_RMAP2);
        float* pw     = (float*)(ws + WS_PW);
        (void)hipMemsetAsync(map, 0xFF, (size_t)NROW * XL * 4, stream);
        (void)hipMemsetAsync(rowcnt, 0, (size_t)NROW * 4, stream);
        build_map2<<<(NP + 255) / 256, 256, 0, stream>>>(coors, map, rowcnt);
        rowfill<<<NROW, 256, 0, stream>>>(pillars, npoints, map, rowcnt, rmap2, pw);
        bigfill<<<NB_BIG, 256, 0, stream>>>(pillars, coors, npoints, rmap2, pw, out);
    } else if (ws_size >= (size_t)NROW * XL * 4) {
        // round-6 proven path
        int* map = (int*)d_ws;
        (void)hipMemsetAsync(map, 0xFF, (size_t)NROW * XL * 4, stream);
        build_map<<<(NP + 255) / 256, 256, 0, stream>>>(coors, map);
        mega_kernel<<<F_NB_MEGA, 256, 0, stream>>>(pillars, coors, npoints, map, out);
    }
}

// Round 10
// 95.593 us; speedup vs baseline: 2.0850x; 1.0870x over previous
//
#include <hip/hip_runtime.h>

// ---------------- problem constants ----------------
constexpr int BS = 4, P_PER = 12000, NP = BS * P_PER;      // 48000 pillars
constexpr int XL = 432, YL = 496, NPTS = 32;
constexpr int XQ = XL / 4;                                 // 108 float4 per row
constexpr int NS = 3 * NPTS;                               // 96 (c,k) slabs
constexpr int YX = YL * XL;                                // 214272

constexpr long long SZ_P   = (long long)NP * NPTS * 3;        // 4,608,000
constexpr long long SZ_C   = (long long)NP * 3;               // 144,000
constexpr long long SZ_N   = NP;                              // 48,000
constexpr long long SZ_ALL = (long long)BS * 3 * NPTS * YL * XL; // 82,280,448
constexpr long long SZ_CTR = (long long)BS * 3 * YL * XL;     // 2,571,264

constexpr long long OFF_ALL = SZ_P + SZ_C + SZ_N;             // 4,800,000
constexpr long long OFF_CTR = OFF_ALL + SZ_ALL;               // 87,080,448

constexpr int MAXJ = 48;    // staged pillars per chunk (row mean 24.2, ~5 sigma)
constexpr int JCAP = 127;   // col2j is int8; j >= JCAP treated as empty

typedef float nt4 __attribute__((ext_vector_type(4)));

// mega-kernel block partition
constexpr int NB_ROW  = BS * YL;                                  // 1984
constexpr int NB_CVT  = (int)((SZ_C / 4 + SZ_N / 4 + 255) / 256); // 188
constexpr int NB_COPY = (int)(SZ_P / 4 / 256);                    // 4500 exact
constexpr int NB_MEGA = NB_ROW + NB_CVT + NB_COPY;                // 6672

// ---------------- map build: cell -> pillar index ----------------
__global__ __launch_bounds__(256) void build_map(const int* __restrict__ coors,
                                                 int* __restrict__ map)
{
    int p = blockIdx.x * 256 + threadIdx.x;
    if (p >= NP) return;
    int b  = coors[3 * p + 0];
    int ix = coors[3 * p + 1];
    int iy = coors[3 * p + 2];
    map[(b * YL + iy) * XL + ix] = p;
}

// ---------------- mega kernel: rows + convert + copy in one grid ----------------
// R6 structure exactly; single variable changed: regular (write-back) stores
// instead of __builtin_nontemporal_store everywhere.
__global__ __launch_bounds__(256) void mega_kernel(
    const float* __restrict__ pillars, const int* __restrict__ coors,
    const int* __restrict__ npoints, const int* __restrict__ map,
    float* __restrict__ out)
{
    const int bid = blockIdx.x;
    const int t   = threadIdx.x;

    if (bid >= NB_ROW) {
        if (bid < NB_ROW + NB_CVT) {
            // outputs 1,2: coors / npoints int32 -> float32
            constexpr int NC = (int)(SZ_C / 4);   // 36000 int4 units
            constexpr int NN = (int)(SZ_N / 4);   // 12000
            int u = (bid - NB_ROW) * 256 + t;
            if (u >= NC + NN) return;
            int4 a; long long dst;
            if (u < NC) { a = reinterpret_cast<const int4*>(coors)[u]; dst = SZ_P / 4 + u; }
            else { a = reinterpret_cast<const int4*>(npoints)[u - NC]; dst = SZ_P / 4 + NC + (u - NC); }
            nt4 o = {(float)a.x, (float)a.y, (float)a.z, (float)a.w};
            reinterpret_cast<nt4*>(out)[dst] = o;
        } else {
            // output region 0: pillars passthrough, fully coalesced
            long long u = (long long)(bid - NB_ROW - NB_CVT) * 256 + t; // < 1,152,000
            nt4 v = reinterpret_cast<const nt4*>(pillars)[u];
            reinterpret_cast<nt4*>(out)[u] = v;
        }
        return;
    }

    // ---- row section: one block per (b, iy) ----
    __shared__ float data[MAXJ][97];        // 18,624 B
    __shared__ float ctr[MAXJ * 3];         //    576 B
    __shared__ signed char col2j[XL];       //    432 B
    __shared__ int jlist[JCAP + 1];         //    512 B
    __shared__ int cnt;

    const int b  = bid / YL;
    const int iy = bid % YL;

    if (t == 0) cnt = 0;
    __syncthreads();

    const int* mrow = map + (b * YL + iy) * XL;
    for (int x = t; x < XL; x += 256) {
        int p = mrow[x];
        if (p >= 0) {
            int j = atomicAdd(&cnt, 1);
            if (j < JCAP) { jlist[j] = p; col2j[x] = (signed char)j; }
            else col2j[x] = -1;
        } else {
            col2j[x] = -1;
        }
    }
    __syncthreads();
    const int nOcc = (cnt < JCAP) ? cnt : JCAP;
    const int nChunks = (nOcc <= MAXJ) ? 1 : (nOcc + MAXJ - 1) / MAXJ;

    float* out_all = out + OFF_ALL + (long long)b * NS * YX + (long long)iy * XL;
    float* out_ctr = out + OFF_CTR + (long long)b * 3 * YX + (long long)iy * XL;

    for (int ch = 0; ch < nChunks; ++ch) {
        const int jbase = ch * MAXJ;
        int chunkN = nOcc - jbase;
        if (chunkN > MAXJ) chunkN = MAXJ;
        if (chunkN < 0) chunkN = 0;

        // stage pillar data: 24 float4 per pillar, read once chip-wide
        for (int i = t; i < chunkN * 24; i += 256) {
            int jl = i / 24, e4 = i % 24;
            float4 v = reinterpret_cast<const float4*>(pillars)
                           [(long long)jlist[jbase + jl] * 24 + e4];
            data[jl][e4 * 4 + 0] = v.x;
            data[jl][e4 * 4 + 1] = v.y;
            data[jl][e4 * 4 + 2] = v.z;
            data[jl][e4 * 4 + 3] = v.w;
        }
        __syncthreads();

        // centers from staged data
        for (int i = t; i < chunkN * 3; i += 256) {
            int jl = i / 3, c = i % 3;
            float s = 0.f;
#pragma unroll
            for (int k = 0; k < NPTS; ++k) s += data[jl][k * 3 + c];
            ctr[i] = s / (float)npoints[jlist[jbase + jl]];
        }
        __syncthreads();

        if (ch == 0) {
            // pillar_all: 96 slab-rows, dense coalesced float4 stores,
            // incremental (s, q, ptr) — no div/mod in the hot loop
            {
                int s = t / XQ;                 // 0..2
                int q = t - s * XQ;
                float* pa = out_all + (long long)s * YX + (long long)q * 4;
                const unsigned int* cj4 = reinterpret_cast<const unsigned int*>(col2j);
                for (int i = t; i < NS * XQ; i += 256) {
                    int e = (s & 31) * 3 + (s >> 5);   // element offset k*3+c
                    unsigned int cc = cj4[q];          // 4 packed int8 slots
                    nt4 o;
                    int j0 = (int)(signed char)(cc & 0xff);
                    int j1 = (int)(signed char)((cc >> 8) & 0xff);
                    int j2 = (int)(signed char)((cc >> 16) & 0xff);
                    int j3 = (int)(signed char)(cc >> 24);
                    o.x = ((unsigned)j0 < MAXJ) ? data[j0][e] : 0.f;
                    o.y = ((unsigned)j1 < MAXJ) ? data[j1][e] : 0.f;
                    o.z = ((unsigned)j2 < MAXJ) ? data[j2][e] : 0.f;
                    o.w = ((unsigned)j3 < MAXJ) ? data[j3][e] : 0.f;
                    *reinterpret_cast<nt4*>(pa) = o;
                    // advance 256 units: s += 2, q += 40, wrap if q >= XQ
                    s += 2; q += 40;
                    long long step = 2LL * YX + 160;
                    if (q >= XQ) { q -= XQ; s += 1; step = 3LL * YX - 272; }
                    pa += step;
                }
            }
            // pillar_center: 3 rows
            {
                const unsigned int* cj4 = reinterpret_cast<const unsigned int*>(col2j);
                for (int i = t; i < 3 * XQ; i += 256) {
                    int c = i / XQ, q = i - c * XQ;
                    unsigned int cc = cj4[q];
                    nt4 o;
                    int j0 = (int)(signed char)(cc & 0xff);
                    int j1 = (int)(signed char)((cc >> 8) & 0xff);
                    int j2 = (int)(signed char)((cc >> 16) & 0xff);
                    int j3 = (int)(signed char)(cc >> 24);
                    o.x = ((unsigned)j0 < MAXJ) ? ctr[j0 * 3 + c] : 0.f;
                    o.y = ((unsigned)j1 < MAXJ) ? ctr[j1 * 3 + c] : 0.f;
                    o.z = ((unsigned)j2 < MAXJ) ? ctr[j2 * 3 + c] : 0.f;
                    o.w = ((unsigned)j3 < MAXJ) ? ctr[j3 * 3 + c] : 0.f;
                    reinterpret_cast<nt4*>(out_ctr + (long long)c * YX)[q] = o;
                }
            }
        } else {
            // overflow chunk (statistically never): scalar rewrites of occupied cols
            for (int i = t; i < XL * NS; i += 256) {
                int x = i % XL, s = i / XL;
                int j = col2j[x];
                if (j >= jbase && j < jbase + chunkN) {
                    int e = (s & 31) * 3 + (s >> 5);
                    out_all[(long long)s * YX + x] = data[j - jbase][e];
                }
            }
            for (int i = t; i < XL * 3; i += 256) {
                int x = i % XL, c = i / XL;
                int j = col2j[x];
                if (j >= jbase && j < jbase + chunkN)
                    out_ctr[(long long)c * YX + x] = ctr[(j - jbase) * 3 + c];
            }
        }
        __syncthreads();
    }
}

// ---------------- fallback path (ws too small): memset + scatter ----------------
__global__ __launch_bounds__(256) void scatter_kernel(
    const float* __restrict__ pillars, const int* __restrict__ coors,
    const int* __restrict__ npoints, float* __restrict__ out)
{
    int tid = blockIdx.x * blockDim.x + threadIdx.x;
    if (tid < NP * NPTS) {
        int p = tid / NPTS, k = tid % NPTS;
        int b = coors[3 * p], ix = coors[3 * p + 1], iy = coors[3 * p + 2];
#pragma unroll
        for (int c = 0; c < 3; ++c) {
            float val = pillars[(long long)p * 96 + k * 3 + c];
            long long e = OFF_ALL + ((((long long)(b * 3 + c) * NPTS + k) * YL + iy) * XL + ix);
            out[e] = val;
        }
    } else if (tid < NP * NPTS + NP) {
        int p = tid - NP * NPTS;
        int b = coors[3 * p], ix = coors[3 * p + 1], iy = coors[3 * p + 2];
        const float4* src = reinterpret_cast<const float4*>(pillars + (long long)p * 96);
        float s[3] = {0.f, 0.f, 0.f};
#pragma unroll
        for (int i = 0; i < 24; ++i) {
            float4 q = src[i];
            s[(4 * i + 0) % 3] += q.x;
            s[(4 * i + 1) % 3] += q.y;
            s[(4 * i + 2) % 3] += q.z;
            s[(4 * i + 3) % 3] += q.w;
        }
        float inv = 1.0f / (float)npoints[p];
#pragma unroll
        for (int c = 0; c < 3; ++c) {
            long long e = OFF_CTR + (((long long)(b * 3 + c) * YL + iy) * XL + ix);
            out[e] = s[c] * inv;
        }
    }
}

__global__ __launch_bounds__(256) void smallcvt_kernel(
    const int* __restrict__ coors, const int* __restrict__ npoints,
    float* __restrict__ out)
{
    constexpr int NC = (int)(SZ_C / 4);
    constexpr int NN = (int)(SZ_N / 4);
    int u = blockIdx.x * 256 + threadIdx.x;
    if (u >= NC + NN) return;
    int4 a; long long dst;
    if (u < NC) { a = reinterpret_cast<const int4*>(coors)[u]; dst = SZ_P / 4 + u; }
    else { a = reinterpret_cast<const int4*>(npoints)[u - NC]; dst = SZ_P / 4 + NC + (u - NC); }
    reinterpret_cast<float4*>(out)[dst] =
        float4{(float)a.x, (float)a.y, (float)a.z, (float)a.w};
}

extern "C" void kernel_launch(void* const* d_in, const int* in_sizes, int n_in,
                              void* d_out, int out_size, void* d_ws, size_t ws_size,
                              hipStream_t stream) {
    const float* pillars = (const float*)d_in[0];
    const int*   coors   = (const int*)d_in[1];
    const int*   npoints = (const int*)d_in[2];
    float*       out     = (float*)d_out;

    const size_t mapBytes = (size_t)BS * YL * XL * sizeof(int);   // 3,428,352

    if (ws_size >= mapBytes) {
        int* map = (int*)d_ws;
        (void)hipMemsetAsync(map, 0xFF, mapBytes, stream);        // all cells -> -1
        build_map<<<(NP + 255) / 256, 256, 0, stream>>>(coors, map);
        mega_kernel<<<NB_MEGA, 256, 0, stream>>>(pillars, coors, npoints, map, out);
    } else {
        // fallback: zero big regions, copy/convert small regions, scatter
        (void)hipMemcpyAsync(out, pillars, (size_t)SZ_P * sizeof(float),
                             hipMemcpyDeviceToDevice, stream);
        (void)hipMemsetAsync(out + OFF_ALL, 0, (size_t)(SZ_ALL + SZ_CTR) * sizeof(float), stream);
        smallcvt_kernel<<<(int)((SZ_C / 4 + SZ_N / 4 + 255) / 256), 256, 0, stream>>>(
            coors, npoints, out);
        int nthr = NP * NPTS + NP;
        scatter_kernel<<<(nthr + 255) / 256, 256, 0, stream>>>(pillars, coors, npoints, out);
    }
}

// Round 11
// 89.820 us; speedup vs baseline: 2.2190x; 1.0643x over previous
//
#include <hip/hip_runtime.h>

// ---------------- problem constants ----------------
constexpr int BS = 4, P_PER = 12000, NP = BS * P_PER;      // 48000 pillars
constexpr int XL = 432, YL = 496, NPTS = 32;
constexpr int XQ = XL / 4;                                 // 108 float4 per row
constexpr int NS = 3 * NPTS;                               // 96 (c,k) slabs
constexpr int YX = YL * XL;                                // 214272

constexpr long long SZ_P   = (long long)NP * NPTS * 3;        // 4,608,000
constexpr long long SZ_C   = (long long)NP * 3;               // 144,000
constexpr long long SZ_N   = NP;                              // 48,000
constexpr long long SZ_ALL = (long long)BS * 3 * NPTS * YL * XL; // 82,280,448
constexpr long long SZ_CTR = (long long)BS * 3 * YL * XL;     // 2,571,264

constexpr long long OFF_ALL = SZ_P + SZ_C + SZ_N;             // 4,800,000
constexpr long long OFF_CTR = OFF_ALL + SZ_ALL;               // 87,080,448

constexpr int MAXJ = 48;    // staged pillars per chunk (row mean 24.2, ~5 sigma)
constexpr int JCAP = 127;   // col2j is int8; j >= JCAP treated as empty

// clang ext-vector float4 — accepted by __builtin_nontemporal_store
typedef float nt4 __attribute__((ext_vector_type(4)));

// mega-kernel block partition
constexpr int NB_ROW  = BS * YL;                                  // 1984
constexpr int NB_CVT  = (int)((SZ_C / 4 + SZ_N / 4 + 255) / 256); // 188
constexpr int NB_COPY = (int)(SZ_P / 4 / 256);                    // 4500 exact
constexpr int NB_MEGA = NB_ROW + NB_CVT + NB_COPY;                // 6672

// ---------------- map build: cell -> pillar index ----------------
__global__ __launch_bounds__(256) void build_map(const int* __restrict__ coors,
                                                 int* __restrict__ map)
{
    int p = blockIdx.x * 256 + threadIdx.x;
    if (p >= NP) return;
    int b  = coors[3 * p + 0];
    int ix = coors[3 * p + 1];
    int iy = coors[3 * p + 2];
    map[(b * YL + iy) * XL + ix] = p;
}

// ---------------- mega kernel: rows + convert + copy in one grid ----------------
__global__ __launch_bounds__(256) void mega_kernel(
    const float* __restrict__ pillars, const int* __restrict__ coors,
    const int* __restrict__ npoints, const int* __restrict__ map,
    float* __restrict__ out)
{
    const int bid = blockIdx.x;
    const int t   = threadIdx.x;

    if (bid >= NB_ROW) {
        if (bid < NB_ROW + NB_CVT) {
            // outputs 1,2: coors / npoints int32 -> float32
            constexpr int NC = (int)(SZ_C / 4);   // 36000 int4 units
            constexpr int NN = (int)(SZ_N / 4);   // 12000
            int u = (bid - NB_ROW) * 256 + t;
            if (u >= NC + NN) return;
            int4 a; long long dst;
            if (u < NC) { a = reinterpret_cast<const int4*>(coors)[u]; dst = SZ_P / 4 + u; }
            else { a = reinterpret_cast<const int4*>(npoints)[u - NC]; dst = SZ_P / 4 + NC + (u - NC); }
            nt4 o = {(float)a.x, (float)a.y, (float)a.z, (float)a.w};
            __builtin_nontemporal_store(o, reinterpret_cast<nt4*>(out) + dst);
        } else {
            // output region 0: pillars passthrough, fully coalesced
            long long u = (long long)(bid - NB_ROW - NB_CVT) * 256 + t; // < 1,152,000
            nt4 v = reinterpret_cast<const nt4*>(pillars)[u];
            __builtin_nontemporal_store(v, reinterpret_cast<nt4*>(out) + u);
        }
        return;
    }

    // ---- row section: one block per (b, iy) ----
    __shared__ float data[MAXJ][97];        // 18,624 B
    __shared__ float ctr[MAXJ * 3];         //    576 B
    __shared__ signed char col2j[XL];       //    432 B
    __shared__ int jlist[JCAP + 1];         //    512 B
    __shared__ int cnt;

    const int b  = bid / YL;
    const int iy = bid % YL;

    if (t == 0) cnt = 0;
    __syncthreads();

    const int* mrow = map + (b * YL + iy) * XL;
    for (int x = t; x < XL; x += 256) {
        int p = mrow[x];
        if (p >= 0) {
            int j = atomicAdd(&cnt, 1);
            if (j < JCAP) { jlist[j] = p; col2j[x] = (signed char)j; }
            else col2j[x] = -1;
        } else {
            col2j[x] = -1;
        }
    }
    __syncthreads();
    const int nOcc = (cnt < JCAP) ? cnt : JCAP;
    const int nChunks = (nOcc <= MAXJ) ? 1 : (nOcc + MAXJ - 1) / MAXJ;

    float* out_all = out + OFF_ALL + (long long)b * NS * YX + (long long)iy * XL;
    float* out_ctr = out + OFF_CTR + (long long)b * 3 * YX + (long long)iy * XL;

    for (int ch = 0; ch < nChunks; ++ch) {
        const int jbase = ch * MAXJ;
        int chunkN = nOcc - jbase;
        if (chunkN > MAXJ) chunkN = MAXJ;
        if (chunkN < 0) chunkN = 0;

        // stage pillar data: 24 float4 per pillar, read once chip-wide
        for (int i = t; i < chunkN * 24; i += 256) {
            int jl = i / 24, e4 = i % 24;
            float4 v = reinterpret_cast<const float4*>(pillars)
                           [(long long)jlist[jbase + jl] * 24 + e4];
            data[jl][e4 * 4 + 0] = v.x;
            data[jl][e4 * 4 + 1] = v.y;
            data[jl][e4 * 4 + 2] = v.z;
            data[jl][e4 * 4 + 3] = v.w;
        }
        __syncthreads();

        // centers from staged data
        for (int i = t; i < chunkN * 3; i += 256) {
            int jl = i / 3, c = i % 3;
            float s = 0.f;
#pragma unroll
            for (int k = 0; k < NPTS; ++k) s += data[jl][k * 3 + c];
            ctr[i] = s / (float)npoints[jlist[jbase + jl]];
        }
        __syncthreads();

        if (ch == 0) {
            // pillar_all: 96 slab-rows, dense coalesced nontemporal float4 stores,
            // incremental (s, q, ptr) — no div/mod in the hot loop
            {
                int s = t / XQ;                 // 0..2
                int q = t - s * XQ;
                float* pa = out_all + (long long)s * YX + (long long)q * 4;
                const unsigned int* cj4 = reinterpret_cast<const unsigned int*>(col2j);
                for (int i = t; i < NS * XQ; i += 256) {
                    int e = (s & 31) * 3 + (s >> 5);   // element offset k*3+c
                    unsigned int cc = cj4[q];          // 4 packed int8 slots
                    nt4 o;
                    int j0 = (int)(signed char)(cc & 0xff);
                    int j1 = (int)(signed char)((cc >> 8) & 0xff);
                    int j2 = (int)(signed char)((cc >> 16) & 0xff);
                    int j3 = (int)(signed char)(cc >> 24);
                    o.x = ((unsigned)j0 < MAXJ) ? data[j0][e] : 0.f;
                    o.y = ((unsigned)j1 < MAXJ) ? data[j1][e] : 0.f;
                    o.z = ((unsigned)j2 < MAXJ) ? data[j2][e] : 0.f;
                    o.w = ((unsigned)j3 < MAXJ) ? data[j3][e] : 0.f;
                    __builtin_nontemporal_store(o, reinterpret_cast<nt4*>(pa));
                    // advance 256 units: s += 2, q += 40, wrap if q >= XQ
                    s += 2; q += 40;
                    long long step = 2LL * YX + 160;
                    if (q >= XQ) { q -= XQ; s += 1; step = 3LL * YX - 272; }
                    pa += step;
                }
            }
            // pillar_center: 3 rows
            {
                const unsigned int* cj4 = reinterpret_cast<const unsigned int*>(col2j);
                for (int i = t; i < 3 * XQ; i += 256) {
                    int c = i / XQ, q = i - c * XQ;
                    unsigned int cc = cj4[q];
                    nt4 o;
                    int j0 = (int)(signed char)(cc & 0xff);
                    int j1 = (int)(signed char)((cc >> 8) & 0xff);
                    int j2 = (int)(signed char)((cc >> 16) & 0xff);
                    int j3 = (int)(signed char)(cc >> 24);
                    o.x = ((unsigned)j0 < MAXJ) ? ctr[j0 * 3 + c] : 0.f;
                    o.y = ((unsigned)j1 < MAXJ) ? ctr[j1 * 3 + c] : 0.f;
                    o.z = ((unsigned)j2 < MAXJ) ? ctr[j2 * 3 + c] : 0.f;
                    o.w = ((unsigned)j3 < MAXJ) ? ctr[j3 * 3 + c] : 0.f;
                    __builtin_nontemporal_store(o,
                        reinterpret_cast<nt4*>(out_ctr + (long long)c * YX + q * 4));
                }
            }
        } else {
            // overflow chunk (statistically never): scalar rewrites of occupied cols
            for (int i = t; i < XL * NS; i += 256) {
                int x = i % XL, s = i / XL;
                int j = col2j[x];
                if (j >= jbase && j < jbase + chunkN) {
                    int e = (s & 31) * 3 + (s >> 5);
                    out_all[(long long)s * YX + x] = data[j - jbase][e];
                }
            }
            for (int i = t; i < XL * 3; i += 256) {
                int x = i % XL, c = i / XL;
                int j = col2j[x];
                if (j >= jbase && j < jbase + chunkN)
                    out_ctr[(long long)c * YX + x] = ctr[(j - jbase) * 3 + c];
            }
        }
        __syncthreads();
    }
}

// ---------------- fallback path (ws too small): memset + scatter ----------------
__global__ __launch_bounds__(256) void scatter_kernel(
    const float* __restrict__ pillars, const int* __restrict__ coors,
    const int* __restrict__ npoints, float* __restrict__ out)
{
    int tid = blockIdx.x * blockDim.x + threadIdx.x;
    if (tid < NP * NPTS) {
        int p = tid / NPTS, k = tid % NPTS;
        int b = coors[3 * p], ix = coors[3 * p + 1], iy = coors[3 * p + 2];
#pragma unroll
        for (int c = 0; c < 3; ++c) {
            float val = pillars[(long long)p * 96 + k * 3 + c];
            long long e = OFF_ALL + ((((long long)(b * 3 + c) * NPTS + k) * YL + iy) * XL + ix);
            out[e] = val;
        }
    } else if (tid < NP * NPTS + NP) {
        int p = tid - NP * NPTS;
        int b = coors[3 * p], ix = coors[3 * p + 1], iy = coors[3 * p + 2];
        const float4* src = reinterpret_cast<const float4*>(pillars + (long long)p * 96);
        float s[3] = {0.f, 0.f, 0.f};
#pragma unroll
        for (int i = 0; i < 24; ++i) {
            float4 q = src[i];
            s[(4 * i + 0) % 3] += q.x;
            s[(4 * i + 1) % 3] += q.y;
            s[(4 * i + 2) % 3] += q.z;
            s[(4 * i + 3) % 3] += q.w;
        }
        float inv = 1.0f / (float)npoints[p];
#pragma unroll
        for (int c = 0; c < 3; ++c) {
            long long e = OFF_CTR + (((long long)(b * 3 + c) * YL + iy) * XL + ix);
            out[e] = s[c] * inv;
        }
    }
}

__global__ __launch_bounds__(256) void smallcvt_kernel(
    const int* __restrict__ coors, const int* __restrict__ npoints,
    float* __restrict__ out)
{
    constexpr int NC = (int)(SZ_C / 4);
    constexpr int NN = (int)(SZ_N / 4);
    int u = blockIdx.x * 256 + threadIdx.x;
    if (u >= NC + NN) return;
    int4 a; long long dst;
    if (u < NC) { a = reinterpret_cast<const int4*>(coors)[u]; dst = SZ_P / 4 + u; }
    else { a = reinterpret_cast<const int4*>(npoints)[u - NC]; dst = SZ_P / 4 + NC + (u - NC); }
    reinterpret_cast<float4*>(out)[dst] =
        float4{(float)a.x, (float)a.y, (float)a.z, (float)a.w};
}

extern "C" void kernel_launch(void* const* d_in, const int* in_sizes, int n_in,
                              void* d_out, int out_size, void* d_ws, size_t ws_size,
                              hipStream_t stream) {
    const float* pillars = (const float*)d_in[0];
    const int*   coors   = (const int*)d_in[1];
    const int*   npoints = (const int*)d_in[2];
    float*       out     = (float*)d_out;

    const size_t mapBytes = (size_t)BS * YL * XL * sizeof(int);   // 3,428,352

    if (ws_size >= mapBytes) {
        int* map = (int*)d_ws;
        (void)hipMemsetAsync(map, 0xFF, mapBytes, stream);        // all cells -> -1
        build_map<<<(NP + 255) / 256, 256, 0, stream>>>(coors, map);
        mega_kernel<<<NB_MEGA, 256, 0, stream>>>(pillars, coors, npoints, map, out);
    } else {
        // fallback: zero big regions, copy/convert small regions, scatter
        (void)hipMemcpyAsync(out, pillars, (size_t)SZ_P * sizeof(float),
                             hipMemcpyDeviceToDevice, stream);
        (void)hipMemsetAsync(out + OFF_ALL, 0, (size_t)(SZ_ALL + SZ_CTR) * sizeof(float), stream);
        smallcvt_kernel<<<(int)((SZ_C / 4 + SZ_N / 4 + 255) / 256), 256, 0, stream>>>(
            coors, npoints, out);
        int nthr = NP * NPTS + NP;
        scatter_kernel<<<(nthr + 255) / 256, 256, 0, stream>>>(pillars, coors, npoints, out);
    }
}